// Round 2
// baseline (1235.333 us; speedup 1.0000x reference)
//
#include <hip/hip_runtime.h>
#include <hip/hip_bf16.h>
#include <cmath>

#define CCH 512
#define TLEN 8192
#define NB 8
#define KFILT 12

typedef unsigned short u16;
typedef __attribute__((ext_vector_type(8))) short short8;
typedef __attribute__((ext_vector_type(8))) unsigned short ushort8;
typedef __attribute__((ext_vector_type(4))) float float4v;
typedef __attribute__((ext_vector_type(4))) int int4v;

struct Filt { float f[KFILT]; };

// ---------- host: kaiser-sinc filter (double precision, matches numpy) ----------
static double bessel_i0(double x) {
    double sum = 1.0, term = 1.0;
    for (int k = 1; k < 40; ++k) {
        double t = (x * 0.5) / k;
        term *= t * t;
        sum += term;
        if (term < 1e-18 * sum) break;
    }
    return sum;
}

static void make_filter(float* out) {
    const int ksize = KFILT, half = KFILT / 2;
    const double cutoff = 0.5 / 2.0;
    const double half_width = 0.6 / 2.0;
    const double delta_f = 4.0 * half_width;
    const double PI = 3.14159265358979323846;
    double A = 2.285 * (half - 1) * PI * delta_f + 7.95;
    double beta;
    if (A > 50.0) beta = 0.1102 * (A - 8.7);
    else if (A >= 21.0) beta = 0.5842 * pow(A - 21.0, 0.4) + 0.07886 * (A - 21.0);
    else beta = 0.0;
    double i0b = bessel_i0(beta);
    double sum = 0.0, f[KFILT];
    for (int n = 0; n < ksize; ++n) {
        double r = (2.0 * n) / (ksize - 1) - 1.0;
        double w = bessel_i0(beta * sqrt(fmax(0.0, 1.0 - r * r))) / i0b;
        double t = (n - half) + 0.5;
        double xx = 2.0 * cutoff * t;
        double snc = (xx == 0.0) ? 1.0 : sin(PI * xx) / (PI * xx);
        f[n] = 2.0 * cutoff * w * snc;
        sum += f[n];
    }
    for (int n = 0; n < ksize; ++n) out[n] = (float)(f[n] / sum);
}

// ---------- device helpers ----------
__device__ __forceinline__ float bf2f(u16 u) {
    return __uint_as_float(((unsigned int)u) << 16);
}
__device__ __forceinline__ u16 f2bf(float f) {
    unsigned int x = __float_as_uint(f);
    unsigned int r = (x + 0x7fffu + ((x >> 16) & 1u)) >> 16;
    return (u16)r;
}
// generic input load: f32 or bf16 depending on runtime flag
__device__ __forceinline__ float ldin(const void* p, size_t i, int isf) {
    return isf ? ((const float*)p)[i] : bf2f(((const u16*)p)[i]);
}
__device__ __forceinline__ void gl_lds16(const void* g, void* s) {
    __builtin_amdgcn_global_load_lds(
        (const __attribute__((address_space(1))) unsigned int*)g,
        (__attribute__((address_space(3))) unsigned int*)s, 16, 0, 0);
}

// ---------- dtype sniffer: bf16-view of f32 data has wild exponents ----------
__global__ __launch_bounds__(256) void k_detect(const u16* __restrict__ x,
                                                int* __restrict__ flag) {
    int tid = threadIdx.x;
    int bad = 0;
    for (int i = tid; i < 4096; i += 256) {
        int e = (x[i] >> 7) & 0xFF;
        if (e >= 0x86) bad++;   // |v| >= 64 or inf/nan as bf16
    }
    for (int off = 32; off > 0; off >>= 1) bad += __shfl_down(bad, off, 64);
    __shared__ int r[4];
    if ((tid & 63) == 0) r[tid >> 6] = bad;
    __syncthreads();
    if (tid == 0) flag[0] = (r[0] + r[1] + r[2] + r[3] >= 64) ? 1 : 0;
}

// ---------- input x -> fp32 xbuf ----------
__global__ __launch_bounds__(256) void k_convert(const void* __restrict__ in,
                                                 float4v* __restrict__ out,
                                                 const int* __restrict__ flg) {
    int i = blockIdx.x * 256 + threadIdx.x;   // < N/8
    if (*flg) {
        const float4v* src = (const float4v*)in;
        out[2 * i] = src[2 * i];
        out[2 * i + 1] = src[2 * i + 1];
    } else {
        ushort8 u = ((const ushort8*)in)[i];
        float4v a, b;
        a.x = bf2f(u[0]); a.y = bf2f(u[1]); a.z = bf2f(u[2]); a.w = bf2f(u[3]);
        b.x = bf2f(u[4]); b.y = bf2f(u[5]); b.z = bf2f(u[6]); b.w = bf2f(u[7]);
        out[2 * i] = a;
        out[2 * i + 1] = b;
    }
}

// ---------- per-out-channel weight-norm scale: g / ||v|| ----------
__global__ __launch_bounds__(256) void k_scales(const void* __restrict__ v,
                                                const void* __restrict__ g,
                                                float* __restrict__ scales,
                                                const int* __restrict__ flg) {
    int isf = *flg;
    int blk = blockIdx.x;            // [0, 3*512)
    int tid = threadIdx.x;
    float s = 0.f;
    for (int i = tid; i < CCH * 3; i += 256) {
        float x = ldin(v, (size_t)blk * (CCH * 3) + i, isf);
        s = fmaf(x, x, s);
    }
    for (int off = 32; off > 0; off >>= 1) s += __shfl_down(s, off, 64);
    __shared__ float red[4];
    if ((tid & 63) == 0) red[tid >> 6] = s;
    __syncthreads();
    if (tid == 0) {
        float tot = red[0] + red[1] + red[2] + red[3];
        scales[blk] = ldin(g, blk, isf) / sqrtf(tot);
    }
}

// ---------- repack weights: Wp[l][tap][co][ci] = v[l][co][ci][tap] (bf16) ----------
__global__ __launch_bounds__(256) void k_repack(const void* __restrict__ v,
                                                u16* __restrict__ wp,
                                                const int* __restrict__ flg) {
    int isf = *flg;
    int l = blockIdx.y;
    int i = blockIdx.x * 256 + threadIdx.x;   // < 3*512*512
    int tap = i >> 18;
    int rem = i & 262143;
    int co = rem >> 9, ci = rem & 511;
    size_t src = (((size_t)l * CCH + co) * CCH + ci) * 3 + tap;
    u16 val = isf ? f2bf(((const float*)v)[src]) : ((const u16*)v)[src];
    wp[(((size_t)l * 3 + tap) * CCH + co) * CCH + ci] = val;
}

// ---------- fused activation1d: up2x (sinc) -> snake -> down2x (sinc) ----------
// x: fp32 [b][c][t]; xt out: bf16 channel-last [b][t][c]
__global__ __launch_bounds__(256) void k_act(const float* __restrict__ x,
                                             const void* __restrict__ alpha,
                                             const void* __restrict__ beta,
                                             int prmofs,
                                             u16* __restrict__ xt, Filt F,
                                             const int* __restrict__ flg) {
    __shared__ float xs[32][45];
    __shared__ float vs[32][75];
    const int isf = *flg;
    const int tid = threadIdx.x;
    const int b = blockIdx.z, c0 = blockIdx.y * 32, t0 = blockIdx.x * 32;
    const int ch = tid >> 3, li = tid & 7;
    const float* xrow = x + ((size_t)(b * CCH + c0 + ch)) * TLEN;
    for (int i = li; i < 44; i += 8) {
        int tg = t0 - 6 + i;
        tg = min(max(tg, 0), TLEN - 1);
        xs[ch][i] = xrow[tg];
    }
    float a = expf(ldin(alpha, prmofs + c0 + ch, isf));
    float invb = 1.0f / (expf(ldin(beta, prmofs + c0 + ch, isf)) + 1e-9f);
    __syncthreads();
    for (int i = li; i < 74; i += 8) {
        int u = 2 * t0 - 5 + i;
        u = min(max(u, 0), 2 * TLEN - 1);
        int s = u >> 1;
        float acc = 0.f;
        if (u & 1) {
            int base = s - t0 + 4;     // x idx s+r-2 -> lds j = s+r-2-(t0-6)
            #pragma unroll
            for (int r = 0; r < 6; ++r) acc = fmaf(F.f[2 * r + 1], xs[ch][base + r], acc);
        } else {
            int base = s - t0 + 3;     // x idx s+r-3
            #pragma unroll
            for (int r = 0; r < 6; ++r) acc = fmaf(F.f[2 * r], xs[ch][base + r], acc);
        }
        acc *= 2.0f;
        float sn = sinf(acc * a);
        vs[ch][i] = fmaf(invb, sn * sn, acc);
    }
    __syncthreads();
    const int c = tid & 31, tq = tid >> 5;
    #pragma unroll
    for (int qq = 0; qq < 4; ++qq) {
        int tl = tq + 8 * qq;
        float s = 0.f;
        #pragma unroll
        for (int j = 0; j < KFILT; ++j) s = fmaf(F.f[j], vs[c][2 * tl + j], s);
        xt[((size_t)b * TLEN + t0 + tl) * CCH + c0 + c] = f2bf(s);
    }
}

// ---------- wn_conv (k=3 dilated) as MFMA implicit GEMM + residual ----------
// xt: bf16 [b][t][c]; wp: bf16 [tap][co][ci]; xbuf: fp32 [b][co][t] in/out
__global__ __launch_bounds__(256) void k_conv(const u16* __restrict__ xt,
                                              const u16* __restrict__ wp,
                                              const float* __restrict__ scales,
                                              const void* __restrict__ bias,
                                              int bofs,
                                              float* __restrict__ xbuf,
                                              void* __restrict__ outp, int d,
                                              const int* __restrict__ flg) {
    // As: 3*128*64 bf16 = 24576 B ; Xs: 768 granules * 16 B = 12288 B (slack-padded)
    __shared__ __align__(16) char smem[24576 + 12288];
    char* As = smem;
    char* Xs = smem + 24576;
    const int isf = *flg;
    const int tid = threadIdx.x;
    const int lane = tid & 63, wid = tid >> 6;
    const int wm = wid & 1, wn = wid >> 1;
    const int b = blockIdx.z, co0 = blockIdx.y * 128, t0 = blockIdx.x * 128;
    const int q = lane >> 4, l15 = lane & 15;
    const int nX = (128 + 2 * d) * 4;              // live X granules
    const bool edge = (t0 == 0) || (t0 + 128 == TLEN);
    const u16* xtb = xt + (size_t)b * TLEN * CCH;

    float4v acc[4][4];
    #pragma unroll
    for (int i = 0; i < 4; ++i)
        #pragma unroll
        for (int j = 0; j < 4; ++j) acc[i][j] = (float4v){0.f, 0.f, 0.f, 0.f};

    for (int ci0 = 0; ci0 < CCH; ci0 += 32) {
        // ---- stage A: 3 taps x 128 co x 32 ci, XOR-swizzled granules, full waves ----
        #pragma unroll
        for (int i = 0; i < 6; ++i) {
            int base = (i * 4 + wid) * 64;
            int L = base + lane;
            int tap = L >> 9;
            int co = (L >> 2) & 127;
            int g = (L & 3) ^ ((co >> 1) & 3);
            gl_lds16(wp + (((size_t)tap * CCH + co0 + co) * CCH + ci0 + g * 8),
                     As + base * 16);
        }
        // ---- stage X: rows t0-d .. (clamped), full waves, zero divergence ----
        #pragma unroll
        for (int i = 0; i < 3; ++i) {
            int base = (i * 4 + wid) * 64;
            int L = base + lane;
            int t = L >> 2;
            int g = (L & 3) ^ ((t >> 1) & 3);
            int tg = min(max(t0 - d + t, 0), TLEN - 1);
            gl_lds16(xtb + ((size_t)tg * CCH + ci0 + g * 8), Xs + base * 16);
        }
        __syncthreads();   // drains vmcnt: async loads have landed
        if (edge) {        // block-uniform: only the two t-edge blocks
            for (int j = tid; j < nX; j += 256) {
                int tg = t0 - d + (j >> 2);
                if (tg < 0 || tg >= TLEN)
                    *(int4v*)(Xs + (size_t)j * 16) = (int4v){0, 0, 0, 0};
            }
            __syncthreads();
        }
        // ---- MFMA: 3 taps x 4x4 frags ----
        #pragma unroll
        for (int tap = 0; tap < 3; ++tap) {
            short8 af[4], bfr[4];
            #pragma unroll
            for (int mi = 0; mi < 4; ++mi) {
                int co = wm * 64 + mi * 16 + l15;
                af[mi] = *(const short8*)(As + tap * 8192 + co * 64 +
                                          ((q ^ ((co >> 1) & 3)) * 16));
            }
            #pragma unroll
            for (int ni = 0; ni < 4; ++ni) {
                int r = wn * 64 + ni * 16 + l15 + tap * d;
                bfr[ni] = *(const short8*)(Xs + r * 64 + ((q ^ ((r >> 1) & 3)) * 16));
            }
            #pragma unroll
            for (int mi = 0; mi < 4; ++mi)
                #pragma unroll
                for (int ni = 0; ni < 4; ++ni)
                    acc[mi][ni] = __builtin_amdgcn_mfma_f32_16x16x32_bf16(
                        af[mi], bfr[ni], acc[mi][ni], 0, 0, 0);
        }
        __syncthreads();
    }

    // ---- epilogue: y = scale*acc + bias + residual ----
    float scl[4][4], bia[4][4];
    #pragma unroll
    for (int mi = 0; mi < 4; ++mi)
        #pragma unroll
        for (int rg = 0; rg < 4; ++rg) {
            int co = co0 + wm * 64 + mi * 16 + q * 4 + rg;
            scl[mi][rg] = scales[co];
            bia[mi][rg] = ldin(bias, bofs + co, isf);
        }
    #pragma unroll
    for (int mi = 0; mi < 4; ++mi)
        #pragma unroll
        for (int ni = 0; ni < 4; ++ni) {
            int tg = t0 + wn * 64 + ni * 16 + l15;
            #pragma unroll
            for (int rg = 0; rg < 4; ++rg) {
                int co = co0 + wm * 64 + mi * 16 + q * 4 + rg;
                size_t idx = ((size_t)(b * CCH + co)) * TLEN + tg;
                float val = fmaf(acc[mi][ni][rg], scl[mi][rg], bia[mi][rg]) + xbuf[idx];
                xbuf[idx] = val;
                if (outp) {
                    if (isf) ((float*)outp)[idx] = val;
                    else ((u16*)outp)[idx] = f2bf(val);
                }
            }
        }
}

// ---------- launcher ----------
extern "C" void kernel_launch(void* const* d_in, const int* in_sizes, int n_in,
                              void* d_out, int out_size, void* d_ws, size_t ws_size,
                              hipStream_t stream) {
    const void* x_in  = d_in[0];
    const void* v_in  = d_in[1];
    const void* g_in  = d_in[2];
    const void* b_in  = d_in[3];
    const void* al_in = d_in[4];
    const void* be_in = d_in[5];

    char* ws = (char*)d_ws;
    float* xbuf   = (float*)ws;                                    // 134217728 B
    u16*   xt     = (u16*)(ws + 134217728);                        // 67108864 B
    u16*   wp     = (u16*)(ws + 134217728 + 67108864);             // 4718592 B
    float* scales = (float*)(ws + 134217728 + 67108864 + 4718592); // 6144 B
    int*   flag   = (int*)(ws + 134217728 + 67108864 + 4718592 + 6144);

    Filt F;
    make_filter(F.f);

    const int N = NB * CCH * TLEN;
    k_detect<<<1, 256, 0, stream>>>((const u16*)x_in, flag);
    k_convert<<<N / 8 / 256, 256, 0, stream>>>(x_in, (float4v*)xbuf, flag);
    k_scales<<<3 * CCH, 256, 0, stream>>>(v_in, g_in, scales, flag);
    k_repack<<<dim3(3072, 3), 256, 0, stream>>>(v_in, wp, flag);

    const int dil[3] = {1, 3, 5};
    for (int l = 0; l < 3; ++l) {
        k_act<<<dim3(TLEN / 32, CCH / 32, NB), 256, 0, stream>>>(
            xbuf, al_in, be_in, l * CCH, xt, F, flag);
        k_conv<<<dim3(TLEN / 128, CCH / 128, NB), 256, 0, stream>>>(
            xt, wp + (size_t)l * 3 * CCH * CCH, scales + l * CCH, b_in, l * CCH,
            xbuf, (l == 2) ? d_out : (void*)nullptr, dil[l], flag);
    }
}

// Round 3
// 1098.318 us; speedup vs baseline: 1.1248x; 1.1248x over previous
//
#include <hip/hip_runtime.h>
#include <hip/hip_bf16.h>
#include <cmath>

#define CCH 512
#define TLEN 8192
#define NB 8
#define KFILT 12

typedef unsigned short u16;
typedef __attribute__((ext_vector_type(8))) short short8;
typedef __attribute__((ext_vector_type(8))) unsigned short ushort8;
typedef __attribute__((ext_vector_type(4))) float float4v;
typedef __attribute__((ext_vector_type(4))) int int4v;

struct Filt { float f[KFILT]; };

// ---------- host: kaiser-sinc filter (double precision, matches numpy) ----------
static double bessel_i0(double x) {
    double sum = 1.0, term = 1.0;
    for (int k = 1; k < 40; ++k) {
        double t = (x * 0.5) / k;
        term *= t * t;
        sum += term;
        if (term < 1e-18 * sum) break;
    }
    return sum;
}

static void make_filter(float* out) {
    const int ksize = KFILT, half = KFILT / 2;
    const double cutoff = 0.5 / 2.0;
    const double half_width = 0.6 / 2.0;
    const double delta_f = 4.0 * half_width;
    const double PI = 3.14159265358979323846;
    double A = 2.285 * (half - 1) * PI * delta_f + 7.95;
    double beta;
    if (A > 50.0) beta = 0.1102 * (A - 8.7);
    else if (A >= 21.0) beta = 0.5842 * pow(A - 21.0, 0.4) + 0.07886 * (A - 21.0);
    else beta = 0.0;
    double i0b = bessel_i0(beta);
    double sum = 0.0, f[KFILT];
    for (int n = 0; n < ksize; ++n) {
        double r = (2.0 * n) / (ksize - 1) - 1.0;
        double w = bessel_i0(beta * sqrt(fmax(0.0, 1.0 - r * r))) / i0b;
        double t = (n - half) + 0.5;
        double xx = 2.0 * cutoff * t;
        double snc = (xx == 0.0) ? 1.0 : sin(PI * xx) / (PI * xx);
        f[n] = 2.0 * cutoff * w * snc;
        sum += f[n];
    }
    for (int n = 0; n < ksize; ++n) out[n] = (float)(f[n] / sum);
}

// ---------- device helpers ----------
__device__ __forceinline__ float bf2f(u16 u) {
    return __uint_as_float(((unsigned int)u) << 16);
}
__device__ __forceinline__ u16 f2bf(float f) {
    unsigned int x = __float_as_uint(f);
    unsigned int r = (x + 0x7fffu + ((x >> 16) & 1u)) >> 16;
    return (u16)r;
}
__device__ __forceinline__ float ldin(const void* p, size_t i, int isf) {
    return isf ? ((const float*)p)[i] : bf2f(((const u16*)p)[i]);
}
__device__ __forceinline__ void gl_lds16(const void* g, void* s) {
    __builtin_amdgcn_global_load_lds(
        (const __attribute__((address_space(1))) unsigned int*)g,
        (__attribute__((address_space(3))) unsigned int*)s, 16, 0, 0);
}

// ---------- dtype sniffer: bf16-view of f32 data has wild exponents ----------
__global__ __launch_bounds__(256) void k_detect(const u16* __restrict__ x,
                                                int* __restrict__ flag) {
    int tid = threadIdx.x;
    int bad = 0;
    for (int i = tid; i < 4096; i += 256) {
        int e = (x[i] >> 7) & 0xFF;
        if (e >= 0x86) bad++;   // |v| >= 64 or inf/nan as bf16
    }
    for (int off = 32; off > 0; off >>= 1) bad += __shfl_down(bad, off, 64);
    __shared__ int r[4];
    if ((tid & 63) == 0) r[tid >> 6] = bad;
    __syncthreads();
    if (tid == 0) flag[0] = (r[0] + r[1] + r[2] + r[3] >= 64) ? 1 : 0;
}

// ---------- per-out-channel weight-norm scale: g / ||v|| ----------
__global__ __launch_bounds__(256) void k_scales(const void* __restrict__ v,
                                                const void* __restrict__ g,
                                                float* __restrict__ scales,
                                                const int* __restrict__ flg) {
    int isf = *flg;
    int blk = blockIdx.x;            // [0, 3*512)
    int tid = threadIdx.x;
    float s = 0.f;
    for (int i = tid; i < CCH * 3; i += 256) {
        float x = ldin(v, (size_t)blk * (CCH * 3) + i, isf);
        s = fmaf(x, x, s);
    }
    for (int off = 32; off > 0; off >>= 1) s += __shfl_down(s, off, 64);
    __shared__ float red[4];
    if ((tid & 63) == 0) red[tid >> 6] = s;
    __syncthreads();
    if (tid == 0) {
        float tot = red[0] + red[1] + red[2] + red[3];
        scales[blk] = ldin(g, blk, isf) / sqrtf(tot);
    }
}

// ---------- repack weights: Wp[l][tap][co][ci] = v[l][co][ci][tap] (bf16) ----------
__global__ __launch_bounds__(256) void k_repack(const void* __restrict__ v,
                                                u16* __restrict__ wp,
                                                const int* __restrict__ flg) {
    int isf = *flg;
    int l = blockIdx.y;
    int i = blockIdx.x * 256 + threadIdx.x;   // < 3*512*512
    int tap = i >> 18;
    int rem = i & 262143;
    int co = rem >> 9, ci = rem & 511;
    size_t src = (((size_t)l * CCH + co) * CCH + ci) * 3 + tap;
    u16 val = isf ? f2bf(((const float*)v)[src]) : ((const u16*)v)[src];
    wp[(((size_t)l * 3 + tap) * CCH + co) * CCH + ci] = val;
}

// ---------- fused activation1d: up2x (sinc) -> snake -> down2x (sinc) ----------
// xsrc: [b][c][t] (bf16 carrier, or input w/ dtype flag at layer 0)
// xt out: bf16 channel-last [b][t][c]
__global__ __launch_bounds__(256) void k_act(const void* __restrict__ xsrc,
                                             const void* __restrict__ alpha,
                                             const void* __restrict__ beta,
                                             int prmofs, u16* __restrict__ xt,
                                             Filt F, const int* __restrict__ flg,
                                             int layer0) {
    __shared__ float xs[32][141];
    __shared__ float vs[32][267];
    const int isf = *flg;
    const int sif = layer0 ? isf : 0;   // carrier is always bf16
    const int tid = threadIdx.x;
    const int b = blockIdx.z, c0 = blockIdx.y * 32, t0 = blockIdx.x * 128;
    const int ch = tid >> 3, li = tid & 7;
    const size_t rowbase = ((size_t)(b * CCH + c0 + ch)) * TLEN;
    for (int i = li; i < 141; i += 8) {
        int tg = min(max(t0 - 6 + i, 0), TLEN - 1);
        xs[ch][i] = sif ? ((const float*)xsrc)[rowbase + tg]
                        : bf2f(((const u16*)xsrc)[rowbase + tg]);
    }
    float a = expf(ldin(alpha, prmofs + c0 + ch, isf));
    float invb = 1.0f / (expf(ldin(beta, prmofs + c0 + ch, isf)) + 1e-9f);
    __syncthreads();
    for (int i = li; i < 267; i += 8) {
        int u = 2 * t0 - 5 + i;
        u = min(max(u, 0), 2 * TLEN - 1);
        int s = u >> 1;
        float acc = 0.f;
        if (u & 1) {
            int base = s - t0 + 4;     // x idx s+r-2 -> lds j = s+r-2-(t0-6)
            #pragma unroll
            for (int r = 0; r < 6; ++r) acc = fmaf(F.f[2 * r + 1], xs[ch][base + r], acc);
        } else {
            int base = s - t0 + 3;     // x idx s+r-3
            #pragma unroll
            for (int r = 0; r < 6; ++r) acc = fmaf(F.f[2 * r], xs[ch][base + r], acc);
        }
        acc *= 2.0f;
        float sn = __sinf(acc * a);
        vs[ch][i] = fmaf(invb, sn * sn, acc);
    }
    __syncthreads();
    const int c = tid & 31, tq = tid >> 5;
    u16* orow = xt + (size_t)b * TLEN * CCH + c0 + c;
    #pragma unroll
    for (int k = 0; k < 16; ++k) {
        int tl = tq + 8 * k;
        float s2 = 0.f;
        #pragma unroll
        for (int j = 0; j < KFILT; ++j) s2 = fmaf(F.f[j], vs[c][2 * tl + j], s2);
        orow[(size_t)(t0 + tl) * CCH] = f2bf(s2);
    }
}

// ---------- wn_conv (k=3 dilated) as MFMA implicit GEMM + residual ----------
// xt: bf16 [b][t][c]; wp: bf16 [tap][co][ci]
// rsrc: residual [b][c][t] (bf16 carrier, or input w/ flag dtype at layer 0)
// wdst: bf16 carrier out (layers 0,1) or null; outp: d_out (layer 2) or null
__global__ __launch_bounds__(256) void k_conv(const u16* __restrict__ xt,
                                              const u16* __restrict__ wp,
                                              const float* __restrict__ scales,
                                              const void* __restrict__ bias,
                                              int bofs,
                                              const void* __restrict__ rsrc,
                                              int layer0,
                                              u16* __restrict__ wdst,
                                              void* __restrict__ outp, int d,
                                              const int* __restrict__ flg) {
    // As: 3*128*64 bf16 = 24576 B ; Xs: 768 granules * 16 B = 12288 B (slack-padded)
    __shared__ __align__(16) char smem[24576 + 12288];
    char* As = smem;
    char* Xs = smem + 24576;
    const int isf = *flg;
    const int rif = layer0 ? isf : 0;
    const int tid = threadIdx.x;
    const int lane = tid & 63, wid = tid >> 6;
    const int wm = wid & 1, wn = wid >> 1;
    const int b = blockIdx.z, co0 = blockIdx.y * 128, t0 = blockIdx.x * 128;
    const int q = lane >> 4, l15 = lane & 15;
    const int nX = (128 + 2 * d) * 4;              // live X granules
    const bool edge = (t0 == 0) || (t0 + 128 == TLEN);
    const u16* xtb = xt + (size_t)b * TLEN * CCH;

    float4v acc[4][4];
    #pragma unroll
    for (int i = 0; i < 4; ++i)
        #pragma unroll
        for (int j = 0; j < 4; ++j) acc[i][j] = (float4v){0.f, 0.f, 0.f, 0.f};

    for (int ci0 = 0; ci0 < CCH; ci0 += 32) {
        // ---- stage A: 3 taps x 128 co x 32 ci, XOR-swizzled granules ----
        #pragma unroll
        for (int i = 0; i < 6; ++i) {
            int base = (i * 4 + wid) * 64;
            int L = base + lane;
            int tap = L >> 9;
            int co = (L >> 2) & 127;
            int g = (L & 3) ^ ((co >> 1) & 3);
            gl_lds16(wp + (((size_t)tap * CCH + co0 + co) * CCH + ci0 + g * 8),
                     As + base * 16);
        }
        // ---- stage X: rows t0-d .. (clamped), full waves, zero divergence ----
        #pragma unroll
        for (int i = 0; i < 3; ++i) {
            int base = (i * 4 + wid) * 64;
            int L = base + lane;
            int t = L >> 2;
            int g = (L & 3) ^ ((t >> 1) & 3);
            int tg = min(max(t0 - d + t, 0), TLEN - 1);
            gl_lds16(xtb + ((size_t)tg * CCH + ci0 + g * 8), Xs + base * 16);
        }
        __syncthreads();   // drains vmcnt
        if (edge) {        // block-uniform: only the two t-edge blocks
            for (int j = tid; j < nX; j += 256) {
                int tg = t0 - d + (j >> 2);
                if (tg < 0 || tg >= TLEN)
                    *(int4v*)(Xs + (size_t)j * 16) = (int4v){0, 0, 0, 0};
            }
            __syncthreads();
        }
        // ---- MFMA: 3 taps x 4x4 frags ----
        #pragma unroll
        for (int tap = 0; tap < 3; ++tap) {
            short8 af[4], bfr[4];
            #pragma unroll
            for (int mi = 0; mi < 4; ++mi) {
                int co = wm * 64 + mi * 16 + l15;
                af[mi] = *(const short8*)(As + tap * 8192 + co * 64 +
                                          ((q ^ ((co >> 1) & 3)) * 16));
            }
            #pragma unroll
            for (int ni = 0; ni < 4; ++ni) {
                int r = wn * 64 + ni * 16 + l15 + tap * d;
                bfr[ni] = *(const short8*)(Xs + r * 64 + ((q ^ ((r >> 1) & 3)) * 16));
            }
            #pragma unroll
            for (int mi = 0; mi < 4; ++mi)
                #pragma unroll
                for (int ni = 0; ni < 4; ++ni)
                    acc[mi][ni] = __builtin_amdgcn_mfma_f32_16x16x32_bf16(
                        af[mi], bfr[ni], acc[mi][ni], 0, 0, 0);
        }
        __syncthreads();
    }

    // ---- epilogue: y = scale*acc + bias + residual ----
    float scl[4][4], bia[4][4];
    #pragma unroll
    for (int mi = 0; mi < 4; ++mi)
        #pragma unroll
        for (int rg = 0; rg < 4; ++rg) {
            int co = co0 + wm * 64 + mi * 16 + q * 4 + rg;
            scl[mi][rg] = scales[co];
            bia[mi][rg] = ldin(bias, bofs + co, isf);
        }
    #pragma unroll
    for (int mi = 0; mi < 4; ++mi)
        #pragma unroll
        for (int ni = 0; ni < 4; ++ni) {
            int tg = t0 + wn * 64 + ni * 16 + l15;
            #pragma unroll
            for (int rg = 0; rg < 4; ++rg) {
                int co = co0 + wm * 64 + mi * 16 + q * 4 + rg;
                size_t idx = ((size_t)(b * CCH + co)) * TLEN + tg;
                float resid = rif ? ((const float*)rsrc)[idx]
                                  : bf2f(((const u16*)rsrc)[idx]);
                float val = fmaf(acc[mi][ni][rg], scl[mi][rg], bia[mi][rg]) + resid;
                if (wdst) {
                    wdst[idx] = f2bf(val);
                } else {
                    if (isf) ((float*)outp)[idx] = val;
                    else ((u16*)outp)[idx] = f2bf(val);
                }
            }
        }
}

// ---------- launcher ----------
extern "C" void kernel_launch(void* const* d_in, const int* in_sizes, int n_in,
                              void* d_out, int out_size, void* d_ws, size_t ws_size,
                              hipStream_t stream) {
    const void* x_in  = d_in[0];
    const void* v_in  = d_in[1];
    const void* g_in  = d_in[2];
    const void* b_in  = d_in[3];
    const void* al_in = d_in[4];
    const void* be_in = d_in[5];

    char* ws = (char*)d_ws;
    u16*   xc     = (u16*)ws;                                     // 67108864 B
    u16*   xt     = (u16*)(ws + 67108864);                        // 67108864 B
    u16*   wp     = (u16*)(ws + 134217728);                       // 4718592 B
    float* scales = (float*)(ws + 134217728 + 4718592);           // 6144 B
    int*   flag   = (int*)(ws + 134217728 + 4718592 + 6144);

    Filt F;
    make_filter(F.f);

    k_detect<<<1, 256, 0, stream>>>((const u16*)x_in, flag);
    k_scales<<<3 * CCH, 256, 0, stream>>>(v_in, g_in, scales, flag);
    k_repack<<<dim3(3072, 3), 256, 0, stream>>>(v_in, wp, flag);

    const int dil[3] = {1, 3, 5};
    for (int l = 0; l < 3; ++l) {
        const void* src = (l == 0) ? x_in : (const void*)xc;
        k_act<<<dim3(TLEN / 128, CCH / 32, NB), 256, 0, stream>>>(
            src, al_in, be_in, l * CCH, xt, F, flag, (l == 0) ? 1 : 0);
        k_conv<<<dim3(TLEN / 128, CCH / 128, NB), 256, 0, stream>>>(
            xt, wp + (size_t)l * 3 * CCH * CCH, scales + l * CCH, b_in, l * CCH,
            src, (l == 0) ? 1 : 0,
            (l == 2) ? (u16*)nullptr : xc,
            (l == 2) ? d_out : nullptr, dil[l], flag);
    }
}